// Round 1
// baseline (63.105 us; speedup 1.0000x reference)
//
#include <hip/hip_runtime.h>

#define EPS 1e-8f

constexpr int D = 384;
constexpr int Q_PER_I = (D * D) / 4;        // 36864 float4 per i-slab
constexpr int P = 4;                        // partial blocks per i
constexpr int Q_PER_PART = Q_PER_I / P;     // 9216 float4 per block
constexpr int THREADS_A = 256;
constexpr int ITERS_A = Q_PER_PART / THREADS_A; // 36
constexpr int J_PER_PART = Q_PER_PART / (D / 4); // 96 j-rows per part

// Kernel A: partial reduction of context[i] = sum_{j,k} a[i,j,k]*y[j]*z[k]
__global__ __launch_bounds__(THREADS_A) void ctx_partial_kernel(
    const float* __restrict__ a,
    const float* __restrict__ y,
    const float* __restrict__ z,
    float* __restrict__ partials) {
  const int b = blockIdx.x;
  const int i = b / P;
  const int part = b - i * P;
  const float4* a4 = reinterpret_cast<const float4*>(a) +
                     (size_t)i * Q_PER_I + (size_t)part * Q_PER_PART;
  const float4* z4 = reinterpret_cast<const float4*>(z);
  const int jbase = part * J_PER_PART;
  const int tid = threadIdx.x;

  float acc = 0.0f;
#pragma unroll 4
  for (int it = 0; it < ITERS_A; ++it) {
    int q = it * THREADS_A + tid;       // [0, 9216)
    int jl = q / 96;                    // local j row (0..95), magic-mul div
    int k4 = q - jl * 96;               // float4 index within row (0..95)
    float4 av = a4[q];
    float4 zv = z4[k4];
    float yj = y[jbase + jl];
    acc += yj * (av.x * zv.x + av.y * zv.y + av.z * zv.z + av.w * zv.w);
  }

  // wave (64-lane) shuffle reduction
  for (int off = 32; off > 0; off >>= 1)
    acc += __shfl_down(acc, off);

  __shared__ float sm[THREADS_A / 64];
  const int lane = tid & 63;
  const int w = tid >> 6;
  if (lane == 0) sm[w] = acc;
  __syncthreads();
  if (tid == 0) {
    float s = 0.0f;
#pragma unroll
    for (int k = 0; k < THREADS_A / 64; ++k) s += sm[k];
    partials[i * P + part] = s;
  }
}

// Kernel B: context[i] = sum_p partials[i][p]; scale by 1/(context[0]+eps)
__global__ __launch_bounds__(D) void ctx_finalize_kernel(
    const float* __restrict__ partials,
    float* __restrict__ ctx_scaled) {
  __shared__ float denom_s;
  const int i = threadIdx.x;
  float s = 0.0f;
#pragma unroll
  for (int p = 0; p < P; ++p) s += partials[i * P + p];
  if (i == 0) denom_s = s;
  __syncthreads();
  const float scale = 1.0f / (denom_s + EPS);
  ctx_scaled[i] = s * scale;
}

// Kernel C: scores[n] = dot(x[n,:], ctx_scaled)  — one row per 64-lane wave
__global__ __launch_bounds__(256) void score_kernel(
    const float* __restrict__ x,
    const float* __restrict__ ctx,
    float* __restrict__ out) {
  const int tid = threadIdx.x;
  const int lane = tid & 63;
  const int w = tid >> 6;
  const int row = blockIdx.x * 4 + w;
  const float4* xr = reinterpret_cast<const float4*>(x) + (size_t)row * (D / 4);
  const float4* c4 = reinterpret_cast<const float4*>(ctx);

  float4 xv = xr[lane];
  float4 cv = c4[lane];
  float s = xv.x * cv.x + xv.y * cv.y + xv.z * cv.z + xv.w * cv.w;
  if (lane < 32) {
    float4 xv2 = xr[64 + lane];
    float4 cv2 = c4[64 + lane];
    s += xv2.x * cv2.x + xv2.y * cv2.y + xv2.z * cv2.z + xv2.w * cv2.w;
  }
  for (int off = 32; off > 0; off >>= 1)
    s += __shfl_down(s, off);
  if (lane == 0) out[row] = s;
}

extern "C" void kernel_launch(void* const* d_in, const int* in_sizes, int n_in,
                              void* d_out, int out_size, void* d_ws, size_t ws_size,
                              hipStream_t stream) {
  const float* x = (const float*)d_in[0];  // [N, 384]
  const float* y = (const float*)d_in[1];  // [384]
  const float* z = (const float*)d_in[2];  // [384]
  const float* a = (const float*)d_in[3];  // [384, 384, 384]
  float* out = (float*)d_out;              // [N]

  const int N = in_sizes[0] / D;           // 65536

  float* partials = (float*)d_ws;          // D*P floats
  float* ctx = partials + D * P;           // D floats

  ctx_partial_kernel<<<D * P, THREADS_A, 0, stream>>>(a, y, z, partials);
  ctx_finalize_kernel<<<1, D, 0, stream>>>(partials, ctx);
  score_kernel<<<N / 4, 256, 0, stream>>>(x, ctx, out);
}